// Round 3
// baseline (524.301 us; speedup 1.0000x reference)
//
#include <hip/hip_runtime.h>
#include <cmath>

// Problem constants (fixed by the reference; active_size == 512)
#define NB   32768
#define DIN  128
#define DMAX 1024
#define A    512

typedef _Float16 half8 __attribute__((ext_vector_type(8)));
typedef float f32x4 __attribute__((ext_vector_type(4)));

// ---------------- ws layout (halves; 2 MB total) ----------------
// [WS_RES_H, +262144) : Wres^T hi, 64 chunks (jb*16+kc) of 4096 h = [128 j][32 k]
// [WS_RES_L, +262144) : Wres^T lo, same
// [WS_PAN + p*131072) : panel p (0=Win, 1..3 = i/f/o gate): 16 chunks (jb*4+kc) hi; lo at +65536
// NOTE: chunks are UNSWIZZLED now (no LDS in the main kernel; fragments are
// read directly from global, 16 B per lane, L2-resident).
#define WS_RES_H 0
#define WS_RES_L 262144
#define WS_PAN   524288

__device__ __forceinline__ float fsigm(float x) { return 1.0f / (1.0f + __expf(-x)); }
__device__ __forceinline__ float ftanh(float x) {
    float e = __expf(-2.0f * fabsf(x));
    float t = (1.0f - e) / (1.0f + e);
    return (x < 0.0f) ? -t : t;
}

// ============================================================================
// Prepass: transpose + fp16 hi/lo split of the WEIGHTS ONLY into ws (2 MB),
// chunked [128 j][32 k]. One thread = one (chunk, j) pair.
// ============================================================================
__global__ __launch_bounds__(256) void prep_w(
    const float* __restrict__ Wres, const float* __restrict__ Win,
    const float* __restrict__ Wg, _Float16* __restrict__ ws)
{
    int tid = blockIdx.x * 256 + threadIdx.x;   // 0 .. 16383
    float v[32];
    size_t dH, dL;
    int j = tid & 127;
    if (tid < 8192) {
        // Wres^T: chunk c = jbb*16+kc covers cols jbb*128+j, rows kc*32..+32
        int c = tid >> 7;
        int jbb = c >> 4, kc = c & 15;
        int col = jbb * 128 + j;
#pragma unroll
        for (int i = 0; i < 32; ++i)
            v[i] = Wres[(size_t)(kc * 32 + i) * DMAX + col];
        dH = WS_RES_H + (size_t)c * 4096;
        dL = WS_RES_L + (size_t)c * 4096;
    } else {
        // panels: c = p*16 + jbb*4 + kc; row jbb*128+j, k = kc*32..+32
        int r = tid - 8192;
        int c = r >> 7;
        int p = c >> 4, cc = c & 15;
        int jbb = cc >> 2, kc = cc & 3;
        int row = jbb * 128 + j;
        const float* s = (p == 0) ? (Win + (size_t)row * DIN + kc * 32)
                                  : (Wg + (size_t)((p - 1) * 512 + row) * DIN + kc * 32);
#pragma unroll
        for (int i = 0; i < 32; ++i) v[i] = s[i];
        dH = WS_PAN + (size_t)p * 131072 + (size_t)(jbb * 4 + kc) * 4096;
        dL = dH + 65536;
    }
#pragma unroll
    for (int gq = 0; gq < 4; ++gq) {
        half8 hh, ll;
#pragma unroll
        for (int i = 0; i < 8; ++i) {
            float x = v[gq * 8 + i];
            _Float16 h = (_Float16)x;
            hh[i] = h;
            ll[i] = (_Float16)(x - (float)h);
        }
        unsigned ho = (unsigned)(j * 32 + gq * 8);   // plain layout
        *(half8*)(ws + dH + ho) = hh;
        *(half8*)(ws + dL + ho) = ll;
    }
}

// ============================================================================
// Fused kernel, LDS-FREE. Block = 128m x 128j, 4 waves 2x2; wave 64x64 as
// 4x4 of mfma_f32_16x16x32_f16, split-fp16 3-product accumulation.
// Per K-step (BK=32):
//   loadB(s)   : 8 x 16B half8 fragment loads straight from ws (L2-hot)
//   loadRaw(s+1): 8 x dwordx4 fp32 A-fragment loads from P/X (prefetch)
//   mmac(s)    : 48 MFMAs (covers the raw-A latency)
//   convA      : in-register hi/lo split -> A frags for s+1
// No __shared__, no barriers: waves free-run, per-wave vmcnt ordering only.
// Frag layouts (verified): A[m=lane&15][k=quad*8+i], B[n=lane&15][k=quad*8+i],
// C/D col=lane&15, row=quad*4+reg.
// ============================================================================
__global__ __launch_bounds__(256, 2) void gser4(
    const float* __restrict__ X,    // [NB, DIN]
    const float* __restrict__ P,    // [NB, DMAX]
    const _Float16* __restrict__ ws,
    const float* __restrict__ lrp, const float* __restrict__ stp,
    float* __restrict__ out)        // [NB, DMAX]
{
    const int t    = threadIdx.x;
    const int lane = t & 63;
    const int w    = t >> 6;
    const int wm   = w & 1, wn = w >> 1;
    const int quad = lane >> 4, l16 = lane & 15;

    // XCD-grouped decode: 4 jb-siblings of one m-panel land on one XCD
    // (round-robin id->XCD) -> shared P rows L2-hit.
    const int id = blockIdx.x;          // 0..1023
    const int x8 = id & 7;
    const int s8 = id >> 3;
    const int jb = s8 & 3;
    const int g  = (s8 >> 2) * 8 + x8;  // m-panel 0..255
    const int m0 = g * 128;
    const int j0 = jb * 128;

    const float* Pblk = P + (size_t)m0 * DMAX;
    const float* Xblk = X + (size_t)m0 * DIN;

    half8 fah[4], fal[4];   // current A fragments (hi/lo)
    half8 fbh[4], fbl[4];   // current B fragments (hi/lo)
    f32x4 ra[4][2];         // prefetched raw fp32 A for next step

    auto loadRaw = [&](int s) {
        const float* base;
        int lda;
        if (s < 16) { base = Pblk + s * 32;       lda = DMAX; }
        else        { base = Xblk + (s & 3) * 32; lda = DIN;  }
#pragma unroll
        for (int ms = 0; ms < 4; ++ms) {
            const float* p = base + (size_t)(wm * 64 + ms * 16 + l16) * lda + quad * 8;
            ra[ms][0] = *(const f32x4*)p;
            ra[ms][1] = *(const f32x4*)(p + 4);
        }
    };

    auto convA = [&]() {
#pragma unroll
        for (int ms = 0; ms < 4; ++ms) {
            half8 hh, ll;
#pragma unroll
            for (int i = 0; i < 4; ++i) {
                float v0 = ra[ms][0][i];
                float v1 = ra[ms][1][i];
                _Float16 h0 = (_Float16)v0;
                _Float16 h1 = (_Float16)v1;
                hh[i]     = h0;
                hh[4 + i] = h1;
                ll[i]     = (_Float16)(v0 - (float)h0);
                ll[4 + i] = (_Float16)(v1 - (float)h1);
            }
            fah[ms] = hh;
            fal[ms] = ll;
        }
    };

    auto loadB = [&](int s) {
        const _Float16 *chH, *chL;
        if (s < 16) {
            chH = ws + WS_RES_H + (size_t)(jb * 16 + s) * 4096;
            chL = ws + WS_RES_L + (size_t)(jb * 16 + s) * 4096;
        } else {
            int p = (s - 16) >> 2, kc = s & 3;
            chH = ws + WS_PAN + (size_t)p * 131072 + (size_t)(jb * 4 + kc) * 4096;
            chL = chH + 65536;
        }
#pragma unroll
        for (int js = 0; js < 4; ++js) {
            int off = (wn * 64 + js * 16 + l16) * 32 + quad * 8;
            fbh[js] = *(const half8*)(chH + off);
            fbl[js] = *(const half8*)(chL + off);
        }
    };

    auto mmac = [&](f32x4 (&C)[4][4]) {
#pragma unroll
        for (int js = 0; js < 4; ++js)
#pragma unroll
            for (int ms = 0; ms < 4; ++ms) {
                C[ms][js] = __builtin_amdgcn_mfma_f32_16x16x32_f16(fah[ms], fbh[js], C[ms][js], 0, 0, 0);
                C[ms][js] = __builtin_amdgcn_mfma_f32_16x16x32_f16(fah[ms], fbl[js], C[ms][js], 0, 0, 0);
                C[ms][js] = __builtin_amdgcn_mfma_f32_16x16x32_f16(fal[ms], fbh[js], C[ms][js], 0, 0, 0);
            }
    };

    // one step: B(s) loads issue first (oldest -> waited without draining A),
    // then A(s+1) prefetch, then MFMA block, then in-register convert.
    auto step = [&](int s, f32x4 (&acc)[4][4], int snext) {
        loadB(s);
        if (snext >= 0) loadRaw(snext);
        mmac(acc);
        if (snext >= 0) convA();
    };

    f32x4 accS[4][4], accG[4][4];
#pragma unroll
    for (int i = 0; i < 4; ++i)
#pragma unroll
        for (int j = 0; j < 4; ++j)
            accS[i][j] = (f32x4){0.f, 0.f, 0.f, 0.f};

    // prologue: raw A(0) + convert (one exposed latency)
    loadRaw(0);
    convA();

    // phase R (K=512, steps 0..15) + W_in (16..19) -> accS
    for (int s = 0; s < 20; ++s) step(s, accS, s + 1);

    // pass 1: i gate (20..23); accS = tanh(sigm(g)*accS)
#pragma unroll
    for (int i = 0; i < 4; ++i)
#pragma unroll
        for (int j = 0; j < 4; ++j)
            accG[i][j] = (f32x4){0.f, 0.f, 0.f, 0.f};
    for (int s = 20; s < 24; ++s) step(s, accG, s + 1);
#pragma unroll
    for (int ms = 0; ms < 4; ++ms)
#pragma unroll
        for (int js = 0; js < 4; ++js)
#pragma unroll
            for (int r = 0; r < 4; ++r)
                accS[ms][js][r] = ftanh(fsigm(accG[ms][js][r]) * accS[ms][js][r]);

    // pass 2: f gate (24..27); accS = (1-leak)*(fg*prev) + leak*accS
#pragma unroll
    for (int i = 0; i < 4; ++i)
#pragma unroll
        for (int j = 0; j < 4; ++j)
            accG[i][j] = (f32x4){0.f, 0.f, 0.f, 0.f};
    for (int s = 24; s < 28; ++s) step(s, accG, s + 1);
    {
        float lk[4];
#pragma unroll
        for (int js = 0; js < 4; ++js)
            lk[js] = fsigm(lrp[j0 + wn * 64 + js * 16 + l16]);
#pragma unroll
        for (int ms = 0; ms < 4; ++ms)
#pragma unroll
            for (int r = 0; r < 4; ++r) {
                int row = m0 + wm * 64 + ms * 16 + quad * 4 + r;
#pragma unroll
                for (int js = 0; js < 4; ++js) {
                    int col = j0 + wn * 64 + js * 16 + l16;
                    float pv = P[(size_t)row * DMAX + col];
                    float fg = fsigm(accG[ms][js][r]);
                    accS[ms][js][r] = (1.0f - lk[js]) * (fg * pv) + lk[js] * accS[ms][js][r];
                }
            }
    }

    // pass 3: o gate (28..31); st = sigm(g)*accS; spike threshold; store
#pragma unroll
    for (int i = 0; i < 4; ++i)
#pragma unroll
        for (int j = 0; j < 4; ++j)
            accG[i][j] = (f32x4){0.f, 0.f, 0.f, 0.f};
    for (int s = 28; s < 32; ++s) step(s, accG, (s < 31) ? s + 1 : -1);
    {
        float thr[4];
#pragma unroll
        for (int js = 0; js < 4; ++js)
            thr[js] = log1pf(__expf(stp[j0 + wn * 64 + js * 16 + l16]));
#pragma unroll
        for (int ms = 0; ms < 4; ++ms)
#pragma unroll
            for (int r = 0; r < 4; ++r) {
                int row = m0 + wm * 64 + ms * 16 + quad * 4 + r;
#pragma unroll
                for (int js = 0; js < 4; ++js) {
                    int col = j0 + wn * 64 + js * 16 + l16;
                    float st = fsigm(accG[ms][js][r]) * accS[ms][js][r];
                    st = (st > thr[js]) ? (st - thr[js]) : st;
                    out[(size_t)row * DMAX + col] = st;
                }
            }
    }

    // zero-pad cols [512,1024): this block covers [512 + jb*128, +128)
#pragma unroll
    for (int i = 0; i < 16; ++i) {
        int s  = t + i * 256;
        int rr = s >> 5, c4 = s & 31;
        *(float4*)(out + (size_t)(m0 + rr) * DMAX + A + jb * 128 + c4 * 4) =
            (float4){0.f, 0.f, 0.f, 0.f};
    }
}

extern "C" void kernel_launch(void* const* d_in, const int* in_sizes, int n_in,
                              void* d_out, int out_size, void* d_ws, size_t ws_size,
                              hipStream_t stream) {
    const float* X    = (const float*)d_in[0];
    const float* P    = (const float*)d_in[1];
    const float* Wres = (const float*)d_in[2];
    const float* Win  = (const float*)d_in[3];
    const float* Wg   = (const float*)d_in[4];
    const float* lrp  = (const float*)d_in[5];
    const float* stp  = (const float*)d_in[6];
    float* out = (float*)d_out;
    _Float16* ws = (_Float16*)d_ws;   // uses 2 MB

    hipLaunchKernelGGL(prep_w, dim3(64), dim3(256), 0, stream,
                       Wres, Win, Wg, ws);
    hipLaunchKernelGGL(gser4, dim3(1024), dim3(256), 0, stream,
                       X, P, ws, lrp, stp, out);
}